// Round 3
// baseline (219.482 us; speedup 1.0000x reference)
//
#include <hip/hip_runtime.h>

// CNN encoder as implicit-im2col GEMM:
//   A(M=32*2040, K=1024) x Wp(K=1024, N=256), Wp[fd][k] = filt[fd]*W_k[fd][k]
//   out = relu(A*Wp + b_k)
// Round 3: occupancy push. 512-thread blocks (8 waves, 4x2), wave tile 32x64
// (acc=32 VGPR), __launch_bounds__(512,4) caps regs at 128 -> 16 waves/CU.
// B prefetched 2 steps deep from L2-resident Wp^T (prep kernel -> d_ws).

#define L_SZ   2048
#define NWIN   2040   // L - F (reference uses L - F)
#define BM     128
#define MT     16

typedef __attribute__((ext_vector_type(8))) short bf16x8;
typedef __attribute__((ext_vector_type(4))) short bf16x4;
typedef __attribute__((ext_vector_type(4))) float f32x4;

static __device__ __forceinline__ short f2bf(float f) {
    union { float f; unsigned u; } v; v.f = f;
    unsigned r = v.u + 0x7FFFu + ((v.u >> 16) & 1u);
    return (short)(r >> 16);
}

// ---- prep: Wp^T[n][k] = bf16(Wk[k][n] * filt[k]),  n<256, k<1024
__global__ __launch_bounds__(256) void prep_w_kernel(
    const float* __restrict__ Wk, const float* __restrict__ filt,
    short* __restrict__ wp)
{
    int g  = blockIdx.x * 256 + threadIdx.x;  // 32768 threads
    int n  = g & 255;
    int kb = (g >> 8) << 3;
    bf16x8 o;
    #pragma unroll
    for (int jj = 0; jj < 8; ++jj)
        o[jj] = f2bf(Wk[(size_t)(kb + jj) * 256 + n] * filt[kb + jj]);
    *reinterpret_cast<bf16x8*>(&wp[(size_t)n * 1024 + kb]) = o;
}

__global__ __launch_bounds__(512, 4) void cnn_enc_kernel(
    const float* __restrict__ ub, const short* __restrict__ wp,
    const float* __restrict__ bk, float* __restrict__ out)
{
    // A slab: 135 rows x 128 d bf16, stride 136 (a-frag quad reads 2-way = free)
    __shared__ short sA[135 * 136];

    const int tid   = threadIdx.x;
    const int bid   = blockIdx.x;
    const int nt    = bid & 1;          // N-tile (0/1)
    const int mt    = (bid >> 1) & 15;  // M-tile
    const int batch = bid >> 5;         // 0..31
    const int l0    = mt * BM;

    // ---- stage A slab once (clamped rows feed only masked-out outputs)
    for (int idx = tid; idx < 135 * 32; idx += 512) {
        int r  = idx >> 5;
        int dc = idx & 31;
        int rg = l0 + r; if (rg > L_SZ - 1) rg = L_SZ - 1;
        const float4 v = *reinterpret_cast<const float4*>(
            ub + (((size_t)batch * L_SZ + rg) << 7) + (dc << 2));
        bf16x4 o;
        o.x = f2bf(v.x); o.y = f2bf(v.y); o.z = f2bf(v.z); o.w = f2bf(v.w);
        *reinterpret_cast<bf16x4*>(&sA[r * 136 + (dc << 2)]) = o;
    }
    __syncthreads();   // the ONLY barrier

    const int lane = tid & 63;
    const int wave = tid >> 6;     // 0..7
    const int wm   = wave >> 1;    // 0..3  (32-row sub-tile)
    const int wn   = wave & 1;     // 0..1  (64-col sub-tile)
    const int t16  = lane & 15;
    const int quad = lane >> 4;

    f32x4 acc[2][4];
    #pragma unroll
    for (int i = 0; i < 2; ++i)
        #pragma unroll
        for (int j = 0; j < 4; ++j)
            acc[i][j] = (f32x4){0.f, 0.f, 0.f, 0.f};

    int aoff[2];
    #pragma unroll
    for (int i = 0; i < 2; ++i)
        aoff[i] = (wm * 32 + i * 16 + t16) * 136 + quad * 8;
    const short* bptr[4];
    #pragma unroll
    for (int j = 0; j < 4; ++j)
        bptr[j] = wp + (size_t)(nt * 128 + wn * 64 + j * 16 + t16) * 1024 + quad * 8;

    // koff (shorts) for step: (step>>2)*128 + (step&3)*32
    #define KOFF(st) (((st) >> 2) * 128 + ((st) & 3) * 32)

    // ---- barrier-free K loop: 32 steps of K=32, B prefetched 2 steps deep
    bf16x8 b0[4], b1[4], b2[4], afr[2];
    #pragma unroll
    for (int j = 0; j < 4; ++j) {
        b0[j] = *reinterpret_cast<const bf16x8*>(bptr[j] + KOFF(0));
        b1[j] = *reinterpret_cast<const bf16x8*>(bptr[j] + KOFF(1));
    }

    #pragma unroll
    for (int step = 0; step < 32; ++step) {
        if (step + 2 < 32) {
            const int koff = KOFF(step + 2);
            #pragma unroll
            for (int j = 0; j < 4; ++j)
                b2[j] = *reinterpret_cast<const bf16x8*>(bptr[j] + koff);
        }
        const int f = step >> 2, s = step & 3;
        #pragma unroll
        for (int i = 0; i < 2; ++i)
            afr[i] = *reinterpret_cast<const bf16x8*>(
                &sA[aoff[i] + f * 136 + s * 32]);
        #pragma unroll
        for (int i = 0; i < 2; ++i)
            #pragma unroll
            for (int j = 0; j < 4; ++j)
                acc[i][j] = __builtin_amdgcn_mfma_f32_16x16x32_bf16(
                    afr[i], b0[j], acc[i][j], 0, 0, 0);
        #pragma unroll
        for (int j = 0; j < 4; ++j) { b0[j] = b1[j]; b1[j] = b2[j]; }
    }

    // ---- epilogue: bias + relu; C/D: col=lane&15, row=quad*4+reg
    #pragma unroll
    for (int j = 0; j < 4; ++j) {
        int n_glob = nt * 128 + wn * 64 + j * 16 + t16;
        float bias = bk[n_glob];
        #pragma unroll
        for (int i = 0; i < 2; ++i) {
            #pragma unroll
            for (int r = 0; r < 4; ++r) {
                int l = l0 + wm * 32 + i * 16 + quad * 4 + r;
                if (l < NWIN) {
                    float v = acc[i][j][r] + bias;
                    out[((size_t)batch * NWIN + l) * 256 + n_glob] =
                        v > 0.f ? v : 0.f;
                }
            }
        }
    }
}

extern "C" void kernel_launch(void* const* d_in, const int* in_sizes, int n_in,
                              void* d_out, int out_size, void* d_ws, size_t ws_size,
                              hipStream_t stream) {
    const float* ub   = (const float*)d_in[0];  // (32,2048,128) fp32
    const float* filt = (const float*)d_in[1];  // (8,128) fp32
    const float* Wk   = (const float*)d_in[2];  // (1024,256) fp32
    const float* bk   = (const float*)d_in[3];  // (256,) fp32
    float* out = (float*)d_out;                 // (32,2040,256) fp32
    short* wp  = (short*)d_ws;                  // 256*1024 bf16 = 512 KB

    hipLaunchKernelGGL(prep_w_kernel, dim3(128), dim3(256), 0, stream,
                       Wk, filt, wp);
    hipLaunchKernelGGL(cnn_enc_kernel, dim3(32 * MT * 2), dim3(512), 0, stream,
                       ub, wp, bk, out);
}

// Round 4
// 147.988 us; speedup vs baseline: 1.4831x; 1.4831x over previous
//
#include <hip/hip_runtime.h>

// CNN encoder as implicit-im2col GEMM:
//   A(M=32*2040, K=1024) x Wp(K=1024, N=256), Wp[fd][k] = filt[fd]*W_k[fd][k]
//   out = relu(A*Wp + b_k)
// Round 4: B staged to LDS via global_load_lds (width=16) in 16KB/BK=64
// chunks (m97 structure, B only; A slab stays LDS-resident). Prep kernel
// re-tiles Wp into chunk-contiguous regions with the XOR bank swizzle baked
// into the stored order so staging is lane-linear and b-frag reads are 2-way.

#define L_SZ   2048
#define NWIN   2040   // L - F (reference uses L - F)
#define BM     128
#define MT     16

typedef __attribute__((ext_vector_type(8))) short bf16x8;
typedef __attribute__((ext_vector_type(4))) short bf16x4;
typedef __attribute__((ext_vector_type(4))) float f32x4;

static __device__ __forceinline__ short f2bf(float f) {
    union { float f; unsigned u; } v; v.f = f;
    unsigned r = v.u + 0x7FFFu + ((v.u >> 16) & 1u);
    return (short)(r >> 16);
}

static __device__ __forceinline__ void gload_lds16(const short* g, short* l) {
    __builtin_amdgcn_global_load_lds(
        (const __attribute__((address_space(1))) unsigned int*)g,
        (__attribute__((address_space(3))) unsigned int*)l, 16, 0, 0);
}

// ---- prep: wp2 re-tiled Wp^T in 32 regions of 16KB = [chunk(16)][nt(2)].
// Region R = chunk*2 + nt holds n' in [0,128), k in [chunk*64, chunk*64+64).
// 16B-slot within region: n'*8 + (c_sub ^ (n'&7));  slot holds
// Wp[nt*128+n'][chunk*64 + c_sub*8 .. +8] with Wp[k][n] = Wk[k][n]*filt[k].
__global__ __launch_bounds__(256) void prep_w_kernel(
    const float* __restrict__ Wk, const float* __restrict__ filt,
    short* __restrict__ wp2)
{
    int g = blockIdx.x * 256 + threadIdx.x;   // 32768 slots of 16B
    int R     = g >> 10;                      // region
    int w     = g & 1023;                     // slot in region
    int np    = w >> 3;                       // n' 0..127
    int pos   = w & 7;                        // stored position
    int chunk = R >> 1;
    int nt    = R & 1;
    int n     = nt * 128 + np;
    int cs    = pos ^ (np & 7);               // logical sub-chunk
    int kb    = chunk * 64 + cs * 8;
    bf16x8 o;
    #pragma unroll
    for (int jj = 0; jj < 8; ++jj)
        o[jj] = f2bf(Wk[(size_t)(kb + jj) * 256 + n] * filt[kb + jj]);
    *reinterpret_cast<bf16x8*>(&wp2[(size_t)g * 8]) = o;
}

__global__ __launch_bounds__(256, 3) void cnn_enc_kernel(
    const float* __restrict__ ub, const short* __restrict__ wp2,
    const float* __restrict__ bk, float* __restrict__ out)
{
    // A slab: 135 rows x 128 d bf16, stride 136 (a-frag quad reads ~2-way)
    __shared__ short sA[135 * 136];   // 36720 B
    // B chunk: 128 n x 64 k bf16, lane-linear staged, XOR-swizzled slots
    __shared__ short sB[8192];        // 16384 B   (total 53104 B -> 3 blk/CU)

    const int tid   = threadIdx.x;
    const int bid   = blockIdx.x;
    const int nt    = bid & 1;          // N-tile (0/1)
    const int mt    = (bid >> 1) & 15;  // M-tile
    const int batch = bid >> 5;         // 0..31
    const int l0    = mt * BM;

    // ---- stage A slab once (clamped rows feed only masked-out outputs)
    for (int idx = tid; idx < 135 * 32; idx += 256) {
        int r  = idx >> 5;
        int dc = idx & 31;
        int rg = l0 + r; if (rg > L_SZ - 1) rg = L_SZ - 1;
        const float4 v = *reinterpret_cast<const float4*>(
            ub + (((size_t)batch * L_SZ + rg) << 7) + (dc << 2));
        bf16x4 o;
        o.x = f2bf(v.x); o.y = f2bf(v.y); o.z = f2bf(v.z); o.w = f2bf(v.w);
        *reinterpret_cast<bf16x4*>(&sA[r * 136 + (dc << 2)]) = o;
    }

    const int lane = tid & 63;
    const int wave = tid >> 6;     // 0..3
    const int wm   = wave >> 1;    // 0..1
    const int wn   = wave & 1;     // 0..1
    const int t16  = lane & 15;
    const int quad = lane >> 4;

    f32x4 acc[4][4];
    #pragma unroll
    for (int i = 0; i < 4; ++i)
        #pragma unroll
        for (int j = 0; j < 4; ++j)
            acc[i][j] = (f32x4){0.f, 0.f, 0.f, 0.f};

    int aoff[4];
    #pragma unroll
    for (int i = 0; i < 4; ++i)
        aoff[i] = (wm * 64 + i * 16 + t16) * 136 + quad * 8;
    int boff[4];                   // sB short-offset minus swizzle part
    #pragma unroll
    for (int j = 0; j < 4; ++j)
        boff[j] = wn * 64 + j * 16 + t16;   // n'

    __syncthreads();   // A slab ready (also covers first sB stage ordering)

    #pragma unroll 1
    for (int chunk = 0; chunk < 16; ++chunk) {
        // ---- stage B chunk: 16 KB lane-linear from chunk-contiguous wp2
        const short* wpbase = wp2 + (size_t)((chunk << 1) | nt) * 8192;
        #pragma unroll
        for (int r = 0; r < 4; ++r) {
            int ubase = r * 256 + wave * 64;           // 16B-unit, wave-uniform
            gload_lds16(wpbase + (ubase + lane) * 8, &sB[ubase * 8]);
        }
        __syncthreads();   // drains vmcnt -> sB ready

        // ---- compute: 2 k-steps of 32, 16 MFMAs each
        #pragma unroll
        for (int s = 0; s < 2; ++s) {
            const int step = (chunk << 1) | s;
            const int f = step >> 2, sd = step & 3;
            bf16x8 a[4], b[4];
            #pragma unroll
            for (int i = 0; i < 4; ++i)
                a[i] = *reinterpret_cast<const bf16x8*>(
                    &sA[aoff[i] + f * 136 + sd * 32]);
            #pragma unroll
            for (int j = 0; j < 4; ++j) {
                int np = boff[j];
                int cs = s * 4 + quad;
                b[j] = *reinterpret_cast<const bf16x8*>(
                    &sB[(np * 8 + (cs ^ (np & 7))) * 8]);
            }
            #pragma unroll
            for (int i = 0; i < 4; ++i)
                #pragma unroll
                for (int j = 0; j < 4; ++j)
                    acc[i][j] = __builtin_amdgcn_mfma_f32_16x16x32_bf16(
                        a[i], b[j], acc[i][j], 0, 0, 0);
        }
        __syncthreads();   // compute done before next stage overwrites sB
    }

    // ---- epilogue: bias + relu; C/D: col=lane&15, row=quad*4+reg
    #pragma unroll
    for (int j = 0; j < 4; ++j) {
        int n_glob = nt * 128 + wn * 64 + j * 16 + t16;
        float bias = bk[n_glob];
        #pragma unroll
        for (int i = 0; i < 4; ++i) {
            #pragma unroll
            for (int r = 0; r < 4; ++r) {
                int l = l0 + wm * 64 + i * 16 + quad * 4 + r;
                if (l < NWIN) {
                    float v = acc[i][j][r] + bias;
                    out[((size_t)batch * NWIN + l) * 256 + n_glob] =
                        v > 0.f ? v : 0.f;
                }
            }
        }
    }
}

extern "C" void kernel_launch(void* const* d_in, const int* in_sizes, int n_in,
                              void* d_out, int out_size, void* d_ws, size_t ws_size,
                              hipStream_t stream) {
    const float* ub   = (const float*)d_in[0];  // (32,2048,128) fp32
    const float* filt = (const float*)d_in[1];  // (8,128) fp32
    const float* Wk   = (const float*)d_in[2];  // (1024,256) fp32
    const float* bk   = (const float*)d_in[3];  // (256,) fp32
    float* out = (float*)d_out;                 // (32,2040,256) fp32
    short* wp2 = (short*)d_ws;                  // 512 KB re-tiled Wp^T

    hipLaunchKernelGGL(prep_w_kernel, dim3(128), dim3(256), 0, stream,
                       Wk, filt, wp2);
    hipLaunchKernelGGL(cnn_enc_kernel, dim3(32 * MT * 2), dim3(256), 0, stream,
                       ub, wp2, bk, out);
}

// Round 5
// 127.428 us; speedup vs baseline: 1.7224x; 1.1613x over previous
//
#include <hip/hip_runtime.h>

// CNN encoder as implicit-im2col GEMM:
//   A(M=32*2040, K=1024) x Wp(K=1024, N=256), Wp[fd][k] = filt[fd]*W_k[fd][k]
//   out = relu(A*Wp + b_k)
// Round 5: BN=256 fusion. 512 blocks (one per batch x m-tile) x 512 threads
// (8 waves, 2x4 grid of 64x64 wave tiles). LDS = A slab 36.7KB + B chunk
// 32KB = 69.5KB -> exactly 2 blocks/CU, zero grid tail. B staged via
// global_load_lds width=16 from chunk-contiguous, bank-swizzle-baked Wp^T.

#define L_SZ   2048
#define NWIN   2040   // L - F (reference uses L - F)
#define BM     128
#define MT     16

typedef __attribute__((ext_vector_type(8))) short bf16x8;
typedef __attribute__((ext_vector_type(4))) short bf16x4;
typedef __attribute__((ext_vector_type(4))) float f32x4;

static __device__ __forceinline__ short f2bf(float f) {
    union { float f; unsigned u; } v; v.f = f;
    unsigned r = v.u + 0x7FFFu + ((v.u >> 16) & 1u);
    return (short)(r >> 16);
}

static __device__ __forceinline__ void gload_lds16(const short* g, short* l) {
    __builtin_amdgcn_global_load_lds(
        (const __attribute__((address_space(1))) unsigned int*)g,
        (__attribute__((address_space(3))) unsigned int*)l, 16, 0, 0);
}

// ---- prep: wp2 = 16 regions (one per 64-K chunk) of 32KB, 2048 slots of 16B.
// Slot w in region R: np = w>>3 (n 0..255), pos = w&7; holds
// Wp[np][R*64 + (pos^(np&7))*8 .. +8], Wp[k][n] = Wk[k][n]*filt[k].
// (XOR swizzle baked in so LDS staging is lane-linear AND b-frag ds_read_b128
//  is 2-way-per-bank = free.)
__global__ __launch_bounds__(256) void prep_w_kernel(
    const float* __restrict__ Wk, const float* __restrict__ filt,
    short* __restrict__ wp2)
{
    int g   = blockIdx.x * 256 + threadIdx.x;  // 32768 slots
    int R   = g >> 11;                         // chunk 0..15
    int w   = g & 2047;
    int np  = w >> 3;                          // n 0..255
    int pos = w & 7;
    int cs  = pos ^ (np & 7);
    int kb  = R * 64 + cs * 8;
    bf16x8 o;
    #pragma unroll
    for (int jj = 0; jj < 8; ++jj)
        o[jj] = f2bf(Wk[(size_t)(kb + jj) * 256 + np] * filt[kb + jj]);
    *reinterpret_cast<bf16x8*>(&wp2[(size_t)g * 8]) = o;
}

__global__ __launch_bounds__(512, 4) void cnn_enc_kernel(
    const float* __restrict__ ub, const short* __restrict__ wp2,
    const float* __restrict__ bk, float* __restrict__ out)
{
    // A slab: 135 rows x 128 d bf16, stride 136 (a-frag quad reads 2-way)
    __shared__ short sA[135 * 136];   // 36720 B
    // B chunk: 256 n x 64 k bf16, lane-linear staged, XOR-swizzled slots
    __shared__ short sB[16384];       // 32768 B  (total 69488 -> 2 blk/CU)

    const int tid   = threadIdx.x;
    const int bid   = blockIdx.x;
    const int mt    = bid & 15;         // M-tile
    const int batch = bid >> 4;         // 0..31
    const int l0    = mt * BM;

    // ---- stage A slab once (clamped rows feed only masked-out outputs)
    for (int idx = tid; idx < 135 * 32; idx += 512) {
        int r  = idx >> 5;
        int dc = idx & 31;
        int rg = l0 + r; if (rg > L_SZ - 1) rg = L_SZ - 1;
        const float4 v = *reinterpret_cast<const float4*>(
            ub + (((size_t)batch * L_SZ + rg) << 7) + (dc << 2));
        bf16x4 o;
        o.x = f2bf(v.x); o.y = f2bf(v.y); o.z = f2bf(v.z); o.w = f2bf(v.w);
        *reinterpret_cast<bf16x4*>(&sA[r * 136 + (dc << 2)]) = o;
    }

    const int lane = tid & 63;
    const int wave = tid >> 6;     // 0..7
    const int wm   = wave >> 2;    // 0..1  (64-row sub-tile)
    const int wn   = wave & 3;     // 0..3  (64-col sub-tile)
    const int t16  = lane & 15;
    const int quad = lane >> 4;

    f32x4 acc[4][4];
    #pragma unroll
    for (int i = 0; i < 4; ++i)
        #pragma unroll
        for (int j = 0; j < 4; ++j)
            acc[i][j] = (f32x4){0.f, 0.f, 0.f, 0.f};

    int aoff[4];
    #pragma unroll
    for (int i = 0; i < 4; ++i)
        aoff[i] = (wm * 64 + i * 16 + t16) * 136 + quad * 8;
    int bnp[4];
    #pragma unroll
    for (int j = 0; j < 4; ++j)
        bnp[j] = wn * 64 + j * 16 + t16;   // n 0..255

    __syncthreads();   // A slab ready

    #pragma unroll 1
    for (int chunk = 0; chunk < 16; ++chunk) {
        // ---- stage B chunk: 32 KB lane-linear from chunk-contiguous wp2
        const short* wpbase = wp2 + (size_t)chunk * 16384;
        #pragma unroll
        for (int r = 0; r < 4; ++r) {
            int ubase = r * 512 + wave * 64;          // 16B-unit, wave-uniform
            gload_lds16(wpbase + (ubase + lane) * 8, &sB[ubase * 8]);
        }
        __syncthreads();   // drains vmcnt -> sB ready

        // ---- compute: 2 k-steps of 32, 16 MFMAs each per wave
        #pragma unroll
        for (int s = 0; s < 2; ++s) {
            const int step = (chunk << 1) | s;
            const int f = step >> 2, sd = step & 3;
            bf16x8 a[4], b[4];
            #pragma unroll
            for (int i = 0; i < 4; ++i)
                a[i] = *reinterpret_cast<const bf16x8*>(
                    &sA[aoff[i] + f * 136 + sd * 32]);
            #pragma unroll
            for (int j = 0; j < 4; ++j) {
                int np = bnp[j];
                int cs = s * 4 + quad;
                b[j] = *reinterpret_cast<const bf16x8*>(
                    &sB[(np * 8 + (cs ^ (np & 7))) * 8]);
            }
            #pragma unroll
            for (int i = 0; i < 4; ++i)
                #pragma unroll
                for (int j = 0; j < 4; ++j)
                    acc[i][j] = __builtin_amdgcn_mfma_f32_16x16x32_bf16(
                        a[i], b[j], acc[i][j], 0, 0, 0);
        }
        __syncthreads();   // compute done before next stage overwrites sB
    }

    // ---- epilogue: bias + relu; C/D: col=lane&15, row=quad*4+reg
    #pragma unroll
    for (int j = 0; j < 4; ++j) {
        int n_glob = wn * 64 + j * 16 + t16;
        float bias = bk[n_glob];
        #pragma unroll
        for (int i = 0; i < 4; ++i) {
            #pragma unroll
            for (int r = 0; r < 4; ++r) {
                int l = l0 + wm * 64 + i * 16 + quad * 4 + r;
                if (l < NWIN) {
                    float v = acc[i][j][r] + bias;
                    out[((size_t)batch * NWIN + l) * 256 + n_glob] =
                        v > 0.f ? v : 0.f;
                }
            }
        }
    }
}

extern "C" void kernel_launch(void* const* d_in, const int* in_sizes, int n_in,
                              void* d_out, int out_size, void* d_ws, size_t ws_size,
                              hipStream_t stream) {
    const float* ub   = (const float*)d_in[0];  // (32,2048,128) fp32
    const float* filt = (const float*)d_in[1];  // (8,128) fp32
    const float* Wk   = (const float*)d_in[2];  // (1024,256) fp32
    const float* bk   = (const float*)d_in[3];  // (256,) fp32
    float* out = (float*)d_out;                 // (32,2040,256) fp32
    short* wp2 = (short*)d_ws;                  // 512 KB re-tiled Wp^T

    hipLaunchKernelGGL(prep_w_kernel, dim3(128), dim3(256), 0, stream,
                       Wk, filt, wp2);
    hipLaunchKernelGGL(cnn_enc_kernel, dim3(32 * MT), dim3(512), 0, stream,
                       ub, wp2, bk, out);
}